// Round 19
// baseline (122.336 us; speedup 1.0000x reference)
//
#include <hip/hip_runtime.h>
#include <hip/hip_bf16.h>
#include <stdint.h>

#define BB_ 2
#define SS_ 2048
#define DIM_ 512
#define NH_ 8
#define QK_ 128
#define VD_ 128

typedef __attribute__((ext_vector_type(8))) short bf16x8;
typedef __attribute__((ext_vector_type(4))) float f32x4;
typedef __attribute__((ext_vector_type(8))) unsigned short ushort8;
typedef __attribute__((ext_vector_type(4))) unsigned short ushort4v;

__device__ __forceinline__ unsigned short f2bf(float f) {
  union { float f; unsigned int u; } v; v.f = f;
  unsigned int r = v.u + 0x7FFFu + ((v.u >> 16) & 1u);  // RNE
  return (unsigned short)(r >> 16);
}

__device__ __forceinline__ float bf2f(unsigned short u) {
  union { unsigned int u; float f; } v; v.u = ((unsigned int)u) << 16;
  return v.f;
}

__device__ __forceinline__ f32x4 mfma16(bf16x8 a, bf16x8 b, f32x4 c) {
  return __builtin_amdgcn_mfma_f32_16x16x32_bf16(a, b, c, 0, 0, 0);
}

// ---------------- fused prep kernel (x-convert + 4 transposes + bias) ----------------

__device__ void transpose_tile(const float* __restrict__ src, unsigned short* __restrict__ dst,
                               int R, int C, int c0, int r0, int tid, float (*t)[65]) {
  const int rr = tid >> 4, cc4 = (tid & 15) * 4;
#pragma unroll
  for (int p = 0; p < 4; p++) {
    float4 v = *reinterpret_cast<const float4*>(src + (size_t)(r0 + rr + p * 16) * C + c0 + cc4);
    t[rr + p * 16][cc4 + 0] = v.x; t[rr + p * 16][cc4 + 1] = v.y;
    t[rr + p * 16][cc4 + 2] = v.z; t[rr + p * 16][cc4 + 3] = v.w;
  }
  __syncthreads();
  const int cl = tid >> 2, rb = (tid & 3) * 16;
#pragma unroll
  for (int g = 0; g < 2; g++) {
    ushort8 o;
#pragma unroll
    for (int j = 0; j < 8; j++) o[j] = f2bf(t[rb + g * 8 + j][cl]);
    *reinterpret_cast<ushort8*>(dst + (size_t)(c0 + cl) * R + r0 + rb + g * 8) = o;
  }
}

__global__ void k_prep(const float* __restrict__ x, unsigned short* __restrict__ xb,
                       const float* __restrict__ wq, const float* __restrict__ wk,
                       const float* __restrict__ wv, unsigned short* __restrict__ wqkv_t,
                       const float* __restrict__ wo, unsigned short* __restrict__ wo_t,
                       const float* __restrict__ bq, const float* __restrict__ bk,
                       const float* __restrict__ bv, float* __restrict__ bias_out) {
  __shared__ float t[64][65];
  const int bid = blockIdx.x, tid = threadIdx.x;
  if (bid < 2048) {                       // x fp32 -> bf16, 4 elems/thread
    const int i = bid * 256 + tid;
    float4 v = reinterpret_cast<const float4*>(x)[i];
    ushort4v o;
    o[0] = f2bf(v.x); o[1] = f2bf(v.y); o[2] = f2bf(v.z); o[3] = f2bf(v.w);
    reinterpret_cast<ushort4v*>(xb)[i] = o;
  } else if (bid < 2432) {                // wq|wk|wv [512][1024] -> [1024][512]^T bf16
    const int tt0 = bid - 2048;
    const int w = tt0 >> 7, tt = tt0 & 127;
    const float* src = (w == 0) ? wq : (w == 1) ? wk : wv;
    transpose_tile(src, wqkv_t + (size_t)w * 1024 * 512, 512, 1024,
                   (tt & 15) * 64, (tt >> 4) * 64, tid, t);
  } else if (bid < 2560) {                // wo [1024][512] -> [512][1024]^T bf16
    const int tt = bid - 2432;
    transpose_tile(wo, wo_t, 1024, 512, (tt & 7) * 64, (tt >> 3) * 64, tid, t);
  } else {                                // bias concat
    const int i = (bid - 2560) * 256 + tid;
    if (i < 1024) bias_out[i] = bq[i];
    else if (i < 2048) bias_out[i] = bk[i - 1024];
    else if (i < 3072) bias_out[i] = bv[i - 2048];
  }
}

// ---------------- GEMM (A row-major [M][K], BT row-major [N][K], both bf16) ----------------
// Staging via global_load_lds width-16. EPI=0 writes pre-swizzled MFMA-fragment
// layouts for attention; q pre-scaled by 1/sqrt(128).

template <int EPI>
__global__ __launch_bounds__(256) void k_gemm_bt(
    const unsigned short* __restrict__ A, const unsigned short* __restrict__ BT,
    const float* __restrict__ bias, int K,
    unsigned short* __restrict__ oq, unsigned short* __restrict__ ok,
    unsigned short* __restrict__ ovt, float* __restrict__ of) {
  __shared__ __align__(16) unsigned short Al[128][32];
  __shared__ __align__(16) unsigned short Bl[128][32];
  const int tid = threadIdx.x;
  const int lane = tid & 63, wave = tid >> 6;
  const int wm = wave >> 1, wn = wave & 1;
  const int lr = lane & 15, lg = lane >> 4;
  const int m0 = blockIdx.y * 128, n0 = blockIdx.x * 128;
  f32x4 acc[4][4] = {};
  const int srow = lane >> 2, scol = (lane & 3) * 8;

  for (int k0 = 0; k0 < K; k0 += 32) {
    __syncthreads();
    {
      const unsigned short* ga = A + (size_t)(m0 + wave * 16 + srow) * K + k0 + scol;
      __builtin_amdgcn_global_load_lds((const unsigned int*)ga,
                                       (unsigned int*)&Al[wave * 16][0], 16, 0, 0);
      __builtin_amdgcn_global_load_lds((const unsigned int*)(ga + (size_t)64 * K),
                                       (unsigned int*)&Al[wave * 16 + 64][0], 16, 0, 0);
      const unsigned short* gb = BT + (size_t)(n0 + wave * 16 + srow) * K + k0 + scol;
      __builtin_amdgcn_global_load_lds((const unsigned int*)gb,
                                       (unsigned int*)&Bl[wave * 16][0], 16, 0, 0);
      __builtin_amdgcn_global_load_lds((const unsigned int*)(gb + (size_t)64 * K),
                                       (unsigned int*)&Bl[wave * 16 + 64][0], 16, 0, 0);
    }
    __syncthreads();
    bf16x8 af[4], bfr[4];
#pragma unroll
    for (int i = 0; i < 4; i++)
      af[i] = *reinterpret_cast<const bf16x8*>(&Al[wm * 64 + i * 16 + lr][lg * 8]);
#pragma unroll
    for (int i = 0; i < 4; i++)
      bfr[i] = *reinterpret_cast<const bf16x8*>(&Bl[wn * 64 + i * 16 + lr][lg * 8]);
#pragma unroll
    for (int i = 0; i < 4; i++)
#pragma unroll
      for (int j = 0; j < 4; j++)
        acc[i][j] = mfma16(af[i], bfr[j], acc[i][j]);
  }

#pragma unroll
  for (int i = 0; i < 4; i++) {
#pragma unroll
    for (int j = 0; j < 4; j++) {
      const int n = n0 + wn * 64 + j * 16 + lr;
      const float bv = bias[n];
      const int mb = m0 + wm * 64 + i * 16 + lg * 4;
      if (EPI == 0) {
        const int region = n >> 10;
        const int h = (n & 1023) >> 7, d = n & 127;
        const int bb = mb >> 11, s0 = mb & 2047;
        const size_t hb = (size_t)(bb * NH_ + h) << 18;
        if (region == 2) {
          ushort4v pk;
#pragma unroll
          for (int r = 0; r < 4; r++) pk[r] = f2bf(acc[i][j][r] + bv);
          const int s32 = s0 >> 5, sg = (s0 >> 3) & 3, e0 = s0 & 7;
          const size_t off = hb + (size_t)(((s32 * 8 + (d >> 4)) * 4 + sg) * 128 + (d & 15) * 8 + e0);
          *reinterpret_cast<ushort4v*>(ovt + off) = pk;
        } else {
          unsigned short* dst = ((region == 0) ? oq : ok) + hb;
          const float qs = (region == 0) ? 0.08838834764831845f : 1.0f;
          const int rt_ = s0 >> 4, c_ = d >> 5, lg_ = (d >> 3) & 3, e_ = d & 7;
          const int lrb = s0 & 15;
#pragma unroll
          for (int r = 0; r < 4; r++)
            dst[(size_t)(((rt_ * 4 + c_) * 64 + lg_ * 16 + lrb + r) * 8 + e_)] =
                f2bf((acc[i][j][r] + bv) * qs);
        }
      } else {
#pragma unroll
        for (int r = 0; r < 4; r++) {
          const int m = mb + r;
          of[(size_t)m * DIM_ + n] = acc[i][j][r] + bv;
        }
      }
    }
  }
}

// ---------------- flash attention: 6-wave blocks, 6-way split-K, 3 waves/SIMD ----------------
// R18 body re-packaged for occupancy: 384-thread blocks (6 waves), grid (8,32,2)
// -> 2 blocks/CU x 6 waves = 12 waves/CU = 3/SIMD (launch_bounds(384,2), reg cap
// ~170). Register diet: sc split into 2 ck-halves (16 regs), V loaded 4-at-a-time
// (16), pf held per kk (8) -> ~164 total incl. 64 AGPR. LDS: Xo(52.2KB) unions
// with P(27.6KB) in one ushort buffer (same-type views; barrier between last P
// use and Xo publish). Uniform work kept: q-tile pair (p,63-p), 33 k-tiles/block.

#define PIDX(w, t, r, c)  ((((w) * 2 + (t)) * 16 + (r)) * 72 + (c))
#define XIDX(w, r, c)     (((w) * 32 + (r)) * 136 + (c))

__global__ __launch_bounds__(384, 2) void k_attn(
    const unsigned short* __restrict__ q, const unsigned short* __restrict__ k,
    const unsigned short* __restrict__ vt, const float* __restrict__ pe,
    unsigned short* __restrict__ att) {
  __shared__ __align__(16) unsigned short SH[26112];  // union: P 13824 ush / Xo 26112 ush
  __shared__ float Xml[6][32];

  const int h = blockIdx.x, p = blockIdx.y, b = blockIdx.z;
  const int lane = threadIdx.x & 63, wave = threadIdx.x >> 6;  // 0..5
  const int lr = lane & 15, lg = lane >> 4;

  const size_t hb = (size_t)(b * NH_ + h) << 18;
  const unsigned short* qfp = q + hb;
  const unsigned short* kfp = k + hb;
  const unsigned short* vfp = vt + hb;
  const float* peh = pe + (size_t)h * SS_ * SS_;

  for (int phase = 0; phase < 2; phase++) {
    const int rt = phase ? (63 - p) : p;     // q-tile32 index
    const int myq0 = rt * 32 + lr;           // tile t's q-row = myq0 + t*16
    const float* pep = peh + (size_t)myq0 * SS_;

    // Q fragments (pre-scaled), coalesced
    bf16x8 qf[2][4];
#pragma unroll
    for (int t = 0; t < 2; t++)
#pragma unroll
      for (int c = 0; c < 4; c++)
        qf[t][c] = *reinterpret_cast<const bf16x8*>(
            qfp + ((size_t)((rt * 2 + t) * 4 + c) << 9) + (lane << 3));

    f32x4 o[2][8] = {};
    float l[2] = {0.f, 0.f};

    const int nkt = (rt >> 1) + 1;
    const int kt_lo = (nkt * wave) / 6;
    const int kt_hi = (nkt * (wave + 1)) / 6;

    for (int kt = kt_lo; kt < kt_hi; kt++) {
      const int kbase = kt * 64;
      const bool diag = (kt == nkt - 1);

      // QK^T + softmax in two ck-halves (sc footprint halved: 16 regs)
#pragma unroll
      for (int ckh = 0; ckh < 2; ckh++) {
        f32x4 sch[2][2];
#pragma unroll
        for (int t = 0; t < 2; t++)
#pragma unroll
          for (int cc = 0; cc < 2; cc++)
            sch[t][cc] = *reinterpret_cast<const f32x4*>(
                pep + (size_t)(t * 16) * SS_ + kbase + (ckh * 2 + cc) * 16 + lg * 4);

        __builtin_amdgcn_s_setprio(1);
#pragma unroll
        for (int cc = 0; cc < 2; cc++) {
          const int ck = ckh * 2 + cc;
#pragma unroll
          for (int c = 0; c < 4; c++) {
            const bf16x8 kf = *reinterpret_cast<const bf16x8*>(
                kfp + ((size_t)((kt * 4 + ck) * 4 + c) << 9) + (lane << 3));
            sch[0][cc] = mfma16(kf, qf[0][c], sch[0][cc]);
            sch[1][cc] = mfma16(kf, qf[1][c], sch[1][cc]);
          }
        }
        __builtin_amdgcn_s_setprio(0);

#pragma unroll
        for (int t = 0; t < 2; t++) {
          const int mq = myq0 + t * 16;
          float rs = 0.f;
#pragma unroll
          for (int cc = 0; cc < 2; cc++) {
            const int ck = ckh * 2 + cc;
#pragma unroll
            for (int r = 0; r < 4; r++) {
              float v = sch[t][cc][r];
              if (diag && (kbase + ck * 16 + lg * 4 + r) > mq) v = -1e30f;
              const float pv = __expf(v);
              sch[t][cc][r] = pv;
              rs += pv;
            }
            ushort4v pk;
#pragma unroll
            for (int r = 0; r < 4; r++) pk[r] = f2bf(sch[t][cc][r]);
            *reinterpret_cast<ushort4v*>(&SH[PIDX(wave, t, lr, ck * 16 + lg * 4)]) = pk;
          }
          l[t] += rs;
        }
      }

      // PV: per kk, hold pf (8 regs), V in sub-groups of 4 (16 regs)
#pragma unroll
      for (int kk = 0; kk < 2; kk++) {
        bf16x8 pf[2];
#pragma unroll
        for (int t = 0; t < 2; t++)
          pf[t] = *reinterpret_cast<const bf16x8*>(&SH[PIDX(wave, t, lr, kk * 32 + lg * 8)]);
#pragma unroll
        for (int sg = 0; sg < 2; sg++) {
          bf16x8 vf4[4];
#pragma unroll
          for (int s4 = 0; s4 < 4; s4++)
            vf4[s4] = *reinterpret_cast<const bf16x8*>(
                vfp + ((size_t)((kt * 2 + kk) * 8 + sg * 4 + s4) << 9) + (lane << 3));
          __builtin_amdgcn_s_setprio(1);
#pragma unroll
          for (int t = 0; t < 2; t++)
#pragma unroll
            for (int s4 = 0; s4 < 4; s4++)
              o[t][sg * 4 + s4] = mfma16(vf4[s4], pf[t], o[t][sg * 4 + s4]);
          __builtin_amdgcn_s_setprio(0);
        }
      }
    }

    // cross-lane l sum (once per phase)
#pragma unroll
    for (int t = 0; t < 2; t++) {
      l[t] += __shfl_xor(l[t], 16);
      l[t] += __shfl_xor(l[t], 32);
    }

    __syncthreads();  // all P reads done before Xo overlays the union buffer

    // publish normalized partials (ALL 6 waves); weight = l
#pragma unroll
    for (int t = 0; t < 2; t++) {
      const float inv = (l[t] > 0.f) ? 1.0f / l[t] : 0.f;
#pragma unroll
      for (int sub = 0; sub < 8; sub++) {
        ushort4v pk;
#pragma unroll
        for (int r = 0; r < 4; r++) pk[r] = f2bf(o[t][sub][r] * inv);
        *reinterpret_cast<ushort4v*>(&SH[XIDX(wave, t * 16 + lr, sub * 16 + lg * 4)]) = pk;
      }
      if (lg == 0) Xml[wave][t * 16 + lr] = l[t];
    }
    __syncthreads();

    // 6-way merge by waves 0-3: rows [wave*8, wave*8+8); 16 d-values/thread
    if (wave < 4) {
      const int mrow = wave * 8 + (lane >> 3);
      float c[6], csum = 0.f;
#pragma unroll
      for (int w = 0; w < 6; w++) { c[w] = Xml[w][mrow]; csum += c[w]; }
      const float invT = 1.0f / csum;   // csum>0: diagonal tile's wave has l>0
#pragma unroll
      for (int half = 0; half < 2; half++) {
        const int dc = (lane & 7) + half * 8;
        float acc[8] = {};
#pragma unroll
        for (int w = 0; w < 6; w++) {
          const ushort8 v = *reinterpret_cast<const ushort8*>(&SH[XIDX(w, mrow, dc * 8)]);
#pragma unroll
          for (int e = 0; e < 8; e++) acc[e] += c[w] * bf2f(v[e]);
        }
        ushort8 outv;
#pragma unroll
        for (int e = 0; e < 8; e++) outv[e] = f2bf(acc[e] * invT);
        *reinterpret_cast<ushort8*>(
            att + (size_t)(b * SS_ + rt * 32 + mrow) * (NH_ * VD_) + h * VD_ + dc * 8) = outv;
      }
    }
    __syncthreads();  // union buffer safe for next phase's P
  }
}

// ---------------- launcher ----------------

extern "C" void kernel_launch(void* const* d_in, const int* in_sizes, int n_in,
                              void* d_out, int out_size, void* d_ws, size_t ws_size,
                              hipStream_t stream) {
  const float* x    = (const float*)d_in[0];
  const float* pe   = (const float*)d_in[3];
  const float* wq_w = (const float*)d_in[4];
  const float* wq_b = (const float*)d_in[5];
  const float* wk_w = (const float*)d_in[6];
  const float* wk_b = (const float*)d_in[7];
  const float* wv_w = (const float*)d_in[8];
  const float* wv_b = (const float*)d_in[9];
  const float* wo_w = (const float*)d_in[10];
  const float* wo_b = (const float*)d_in[11];
  float* out = (float*)d_out;

  char* ws = (char*)d_ws;
  unsigned short* x_bf   = (unsigned short*)(ws);                 // 4 MB
  unsigned short* wqkv_t = (unsigned short*)(ws + 4194304);       // 3 MB
  unsigned short* wo_t   = (unsigned short*)(ws + 7340032);       // 1 MB
  float*          qkv_b  = (float*)(ws + 8388608);                // 12 KB
  unsigned short* qb     = (unsigned short*)(ws + 8400896);       // 8 MB (Qf)
  unsigned short* kb     = (unsigned short*)(ws + 16789504);      // 8 MB (Kf)
  unsigned short* vtb    = (unsigned short*)(ws + 25178112);      // 8 MB (Vf)
  unsigned short* attb   = (unsigned short*)(ws + 33566720);      // 8 MB

  k_prep<<<2572, 256, 0, stream>>>(x, x_bf, wq_w, wk_w, wv_w, wqkv_t,
                                   wo_w, wo_t, wq_b, wk_b, wv_b, qkv_b);

  dim3 g1(24, 32);
  k_gemm_bt<0><<<g1, 256, 0, stream>>>(x_bf, wqkv_t, qkv_b, 512, qb, kb, vtb, nullptr);

  dim3 g2(NH_, 32, BB_);  // x=head -> XCD = head; uniform-work blocks
  k_attn<<<g2, 384, 0, stream>>>(qb, kb, vtb, pe, attb);

  dim3 g3(4, 32);
  k_gemm_bt<1><<<g3, 256, 0, stream>>>(attb, wo_t, wo_b, 1024, nullptr, nullptr, nullptr, out);
}

// Round 20
// 98.475 us; speedup vs baseline: 1.2423x; 1.2423x over previous
//
#include <hip/hip_runtime.h>
#include <hip/hip_bf16.h>
#include <stdint.h>

#define BB_ 2
#define SS_ 2048
#define DIM_ 512
#define NH_ 8
#define QK_ 128
#define VD_ 128

typedef __attribute__((ext_vector_type(8))) short bf16x8;
typedef __attribute__((ext_vector_type(4))) float f32x4;
typedef __attribute__((ext_vector_type(8))) unsigned short ushort8;
typedef __attribute__((ext_vector_type(4))) unsigned short ushort4v;

__device__ __forceinline__ unsigned short f2bf(float f) {
  union { float f; unsigned int u; } v; v.f = f;
  unsigned int r = v.u + 0x7FFFu + ((v.u >> 16) & 1u);  // RNE
  return (unsigned short)(r >> 16);
}

__device__ __forceinline__ float bf2f(unsigned short u) {
  union { unsigned int u; float f; } v; v.u = ((unsigned int)u) << 16;
  return v.f;
}

__device__ __forceinline__ f32x4 mfma16(bf16x8 a, bf16x8 b, f32x4 c) {
  return __builtin_amdgcn_mfma_f32_16x16x32_bf16(a, b, c, 0, 0, 0);
}

// ---------------- fused prep kernel (x-convert + 4 transposes + bias) ----------------

__device__ void transpose_tile(const float* __restrict__ src, unsigned short* __restrict__ dst,
                               int R, int C, int c0, int r0, int tid, float (*t)[65]) {
  const int rr = tid >> 4, cc4 = (tid & 15) * 4;
#pragma unroll
  for (int p = 0; p < 4; p++) {
    float4 v = *reinterpret_cast<const float4*>(src + (size_t)(r0 + rr + p * 16) * C + c0 + cc4);
    t[rr + p * 16][cc4 + 0] = v.x; t[rr + p * 16][cc4 + 1] = v.y;
    t[rr + p * 16][cc4 + 2] = v.z; t[rr + p * 16][cc4 + 3] = v.w;
  }
  __syncthreads();
  const int cl = tid >> 2, rb = (tid & 3) * 16;
#pragma unroll
  for (int g = 0; g < 2; g++) {
    ushort8 o;
#pragma unroll
    for (int j = 0; j < 8; j++) o[j] = f2bf(t[rb + g * 8 + j][cl]);
    *reinterpret_cast<ushort8*>(dst + (size_t)(c0 + cl) * R + r0 + rb + g * 8) = o;
  }
}

__global__ void k_prep(const float* __restrict__ x, unsigned short* __restrict__ xb,
                       const float* __restrict__ wq, const float* __restrict__ wk,
                       const float* __restrict__ wv, unsigned short* __restrict__ wqkv_t,
                       const float* __restrict__ wo, unsigned short* __restrict__ wo_t,
                       const float* __restrict__ bq, const float* __restrict__ bk,
                       const float* __restrict__ bv, float* __restrict__ bias_out) {
  __shared__ float t[64][65];
  const int bid = blockIdx.x, tid = threadIdx.x;
  if (bid < 2048) {                       // x fp32 -> bf16, 4 elems/thread
    const int i = bid * 256 + tid;
    float4 v = reinterpret_cast<const float4*>(x)[i];
    ushort4v o;
    o[0] = f2bf(v.x); o[1] = f2bf(v.y); o[2] = f2bf(v.z); o[3] = f2bf(v.w);
    reinterpret_cast<ushort4v*>(xb)[i] = o;
  } else if (bid < 2432) {                // wq|wk|wv [512][1024] -> [1024][512]^T bf16
    const int tt0 = bid - 2048;
    const int w = tt0 >> 7, tt = tt0 & 127;
    const float* src = (w == 0) ? wq : (w == 1) ? wk : wv;
    transpose_tile(src, wqkv_t + (size_t)w * 1024 * 512, 512, 1024,
                   (tt & 15) * 64, (tt >> 4) * 64, tid, t);
  } else if (bid < 2560) {                // wo [1024][512] -> [512][1024]^T bf16
    const int tt = bid - 2432;
    transpose_tile(wo, wo_t, 1024, 512, (tt & 7) * 64, (tt >> 3) * 64, tid, t);
  } else {                                // bias concat
    const int i = (bid - 2560) * 256 + tid;
    if (i < 1024) bias_out[i] = bq[i];
    else if (i < 2048) bias_out[i] = bk[i - 1024];
    else if (i < 3072) bias_out[i] = bv[i - 2048];
  }
}

// ---------------- QKV GEMM (A row-major [M][K], BT row-major [N][K], both bf16) ----------------
// Staging via global_load_lds width-16. Writes pre-swizzled MFMA-fragment
// layouts for attention; q pre-scaled by 1/sqrt(128).

__global__ __launch_bounds__(256) void k_gemm_qkv(
    const unsigned short* __restrict__ A, const unsigned short* __restrict__ BT,
    const float* __restrict__ bias, int K,
    unsigned short* __restrict__ oq, unsigned short* __restrict__ ok,
    unsigned short* __restrict__ ovt) {
  __shared__ __align__(16) unsigned short Al[128][32];
  __shared__ __align__(16) unsigned short Bl[128][32];
  const int tid = threadIdx.x;
  const int lane = tid & 63, wave = tid >> 6;
  const int wm = wave >> 1, wn = wave & 1;
  const int lr = lane & 15, lg = lane >> 4;
  const int m0 = blockIdx.y * 128, n0 = blockIdx.x * 128;
  f32x4 acc[4][4] = {};
  const int srow = lane >> 2, scol = (lane & 3) * 8;

  for (int k0 = 0; k0 < K; k0 += 32) {
    __syncthreads();
    {
      const unsigned short* ga = A + (size_t)(m0 + wave * 16 + srow) * K + k0 + scol;
      __builtin_amdgcn_global_load_lds((const unsigned int*)ga,
                                       (unsigned int*)&Al[wave * 16][0], 16, 0, 0);
      __builtin_amdgcn_global_load_lds((const unsigned int*)(ga + (size_t)64 * K),
                                       (unsigned int*)&Al[wave * 16 + 64][0], 16, 0, 0);
      const unsigned short* gb = BT + (size_t)(n0 + wave * 16 + srow) * K + k0 + scol;
      __builtin_amdgcn_global_load_lds((const unsigned int*)gb,
                                       (unsigned int*)&Bl[wave * 16][0], 16, 0, 0);
      __builtin_amdgcn_global_load_lds((const unsigned int*)(gb + (size_t)64 * K),
                                       (unsigned int*)&Bl[wave * 16 + 64][0], 16, 0, 0);
    }
    __syncthreads();
    bf16x8 af[4], bfr[4];
#pragma unroll
    for (int i = 0; i < 4; i++)
      af[i] = *reinterpret_cast<const bf16x8*>(&Al[wm * 64 + i * 16 + lr][lg * 8]);
#pragma unroll
    for (int i = 0; i < 4; i++)
      bfr[i] = *reinterpret_cast<const bf16x8*>(&Bl[wn * 64 + i * 16 + lr][lg * 8]);
#pragma unroll
    for (int i = 0; i < 4; i++)
#pragma unroll
      for (int j = 0; j < 4; j++)
        acc[i][j] = mfma16(af[i], bfr[j], acc[i][j]);
  }

#pragma unroll
  for (int i = 0; i < 4; i++) {
#pragma unroll
    for (int j = 0; j < 4; j++) {
      const int n = n0 + wn * 64 + j * 16 + lr;
      const float bv = bias[n];
      const int mb = m0 + wm * 64 + i * 16 + lg * 4;
      const int region = n >> 10;
      const int h = (n & 1023) >> 7, d = n & 127;
      const int bb = mb >> 11, s0 = mb & 2047;
      const size_t hb = (size_t)(bb * NH_ + h) << 18;
      if (region == 2) {
        ushort4v pk;
#pragma unroll
        for (int r = 0; r < 4; r++) pk[r] = f2bf(acc[i][j][r] + bv);
        const int s32 = s0 >> 5, sg = (s0 >> 3) & 3, e0 = s0 & 7;
        const size_t off = hb + (size_t)(((s32 * 8 + (d >> 4)) * 4 + sg) * 128 + (d & 15) * 8 + e0);
        *reinterpret_cast<ushort4v*>(ovt + off) = pk;
      } else {
        unsigned short* dst = ((region == 0) ? oq : ok) + hb;
        const float qs = (region == 0) ? 0.08838834764831845f : 1.0f;
        const int rt_ = s0 >> 4, c_ = d >> 5, lg_ = (d >> 3) & 3, e_ = d & 7;
        const int lrb = s0 & 15;
#pragma unroll
        for (int r = 0; r < 4; r++)
          dst[(size_t)(((rt_ * 4 + c_) * 64 + lg_ * 16 + lrb + r) * 8 + e_)] =
              f2bf((acc[i][j][r] + bv) * qs);
      }
    }
  }
}

// ---------------- output GEMM: 128M x 64N tiles -> 256 blocks (full machine) ----------------
// A [M][K] bf16, BT [N][K] bf16, out fp32 [M][N]+bias. Each wave: 32 rows x 64 cols.

__global__ __launch_bounds__(256) void k_gemm_o64(
    const unsigned short* __restrict__ A, const unsigned short* __restrict__ BT,
    const float* __restrict__ bias, int K, float* __restrict__ of) {
  __shared__ __align__(16) unsigned short Al[128][32];
  __shared__ __align__(16) unsigned short Bl[64][32];
  const int tid = threadIdx.x;
  const int lane = tid & 63, wave = tid >> 6;
  const int lr = lane & 15, lg = lane >> 4;
  const int m0 = blockIdx.y * 128, n0 = blockIdx.x * 64;
  f32x4 acc[2][4] = {};
  const int srow = lane >> 2, scol = (lane & 3) * 8;

  for (int k0 = 0; k0 < K; k0 += 32) {
    __syncthreads();
    {
      const unsigned short* ga = A + (size_t)(m0 + wave * 16 + srow) * K + k0 + scol;
      __builtin_amdgcn_global_load_lds((const unsigned int*)ga,
                                       (unsigned int*)&Al[wave * 16][0], 16, 0, 0);
      __builtin_amdgcn_global_load_lds((const unsigned int*)(ga + (size_t)64 * K),
                                       (unsigned int*)&Al[wave * 16 + 64][0], 16, 0, 0);
      const unsigned short* gb = BT + (size_t)(n0 + wave * 16 + srow) * K + k0 + scol;
      __builtin_amdgcn_global_load_lds((const unsigned int*)gb,
                                       (unsigned int*)&Bl[wave * 16][0], 16, 0, 0);
    }
    __syncthreads();
    bf16x8 af[2], bfr[4];
#pragma unroll
    for (int i = 0; i < 2; i++)
      af[i] = *reinterpret_cast<const bf16x8*>(&Al[wave * 32 + i * 16 + lr][lg * 8]);
#pragma unroll
    for (int j = 0; j < 4; j++)
      bfr[j] = *reinterpret_cast<const bf16x8*>(&Bl[j * 16 + lr][lg * 8]);
#pragma unroll
    for (int i = 0; i < 2; i++)
#pragma unroll
      for (int j = 0; j < 4; j++)
        acc[i][j] = mfma16(af[i], bfr[j], acc[i][j]);
  }

#pragma unroll
  for (int i = 0; i < 2; i++) {
#pragma unroll
    for (int j = 0; j < 4; j++) {
      const int n = n0 + j * 16 + lr;
      const float bv = bias[n];
      const int mb = m0 + wave * 32 + i * 16 + lg * 4;
#pragma unroll
      for (int r = 0; r < 4; r++)
        of[(size_t)(mb + r) * DIM_ + n] = acc[i][j][r] + bv;
    }
  }
}

// ---------------- flash attention: uniform-work blocks, 4-way split-K, m=0 softmax ----------------
// R18 body (best known): pe first (QK^T C-operand), K interleaved with MFMA,
// V after QK (consumed at PV), m=0 softmax (no reductions in-loop), uniform
// work (q-tile pair (p,63-p), 33 k-tiles/block), XCD=head, exact l-weighted merge.

__global__ __launch_bounds__(256, 2) void k_attn(
    const unsigned short* __restrict__ q, const unsigned short* __restrict__ k,
    const unsigned short* __restrict__ vt, const float* __restrict__ pe,
    unsigned short* __restrict__ att) {
  __shared__ __align__(16) unsigned short P[4][2][16][72];   // 18 KB, wave-private
  __shared__ __align__(16) unsigned short Xo[4][32][136];    // 34.8 KB partials
  __shared__ float Xml[4][32];                               // l only

  const int h = blockIdx.x, p = blockIdx.y, b = blockIdx.z;
  const int lane = threadIdx.x & 63, wave = threadIdx.x >> 6;
  const int lr = lane & 15, lg = lane >> 4;

  const size_t hb = (size_t)(b * NH_ + h) << 18;
  const unsigned short* qfp = q + hb;
  const unsigned short* kfp = k + hb;
  const unsigned short* vfp = vt + hb;
  const float* peh = pe + (size_t)h * SS_ * SS_;

  for (int phase = 0; phase < 2; phase++) {
    const int rt = phase ? (63 - p) : p;     // q-tile32 index
    const int myq0 = rt * 32 + lr;           // tile t's q-row = myq0 + t*16
    const float* pep = peh + (size_t)myq0 * SS_;

    // Q fragments (pre-scaled), coalesced
    bf16x8 qf[2][4];
#pragma unroll
    for (int t = 0; t < 2; t++)
#pragma unroll
      for (int c = 0; c < 4; c++)
        qf[t][c] = *reinterpret_cast<const bf16x8*>(
            qfp + ((size_t)((rt * 2 + t) * 4 + c) << 9) + (lane << 3));

    f32x4 o[2][8] = {};
    float l[2] = {0.f, 0.f};    // per-lane partial row-sums

    const int nkt = (rt >> 1) + 1;
    const int kt_lo = (nkt * wave) >> 2;
    const int kt_hi = (nkt * (wave + 1)) >> 2;

    for (int kt = kt_lo; kt < kt_hi; kt++) {
      const int kbase = kt * 64;

      // 1) pe FIRST (chain head: consumed as the QK^T C-operand)
      f32x4 sc[2][4];
#pragma unroll
      for (int t = 0; t < 2; t++)
#pragma unroll
        for (int ck = 0; ck < 4; ck++)
          sc[t][ck] = *reinterpret_cast<const f32x4*>(
              pep + (size_t)(t * 16) * SS_ + kbase + ck * 16 + lg * 4);

      // 2) QK^T (K loads interleaved, consumed immediately)
      __builtin_amdgcn_s_setprio(1);
#pragma unroll
      for (int ck = 0; ck < 4; ck++) {
#pragma unroll
        for (int c = 0; c < 4; c++) {
          const bf16x8 kf = *reinterpret_cast<const bf16x8*>(
              kfp + ((size_t)((kt * 4 + ck) * 4 + c) << 9) + (lane << 3));
          sc[0][ck] = mfma16(kf, qf[0][c], sc[0][ck]);
          sc[1][ck] = mfma16(kf, qf[1][c], sc[1][ck]);
        }
      }
      __builtin_amdgcn_s_setprio(0);

      // 3) V^T fragments kk=0 NOW (consumed at PV; QK+softmax covers latency)
      bf16x8 vf[8];
#pragma unroll
      for (int sub = 0; sub < 8; sub++)
        vf[sub] = *reinterpret_cast<const bf16x8*>(
            vfp + ((size_t)((kt * 2) * 8 + sub) << 9) + (lane << 3));

      // 4) causal mask + exp (m == 0 constant: no reduction, no rescale)
      const bool diag = (kt == nkt - 1);
#pragma unroll
      for (int t = 0; t < 2; t++) {
        const int mq = myq0 + t * 16;
        float rs0 = 0.f, rs1 = 0.f;
#pragma unroll
        for (int ck = 0; ck < 4; ck++) {
#pragma unroll
          for (int r = 0; r < 4; r++) {
            float v = sc[t][ck][r];
            if (diag && (kbase + ck * 16 + lg * 4 + r) > mq) v = -1e30f;
            const float pv = __expf(v);
            sc[t][ck][r] = pv;
            if (ck & 1) rs1 += pv; else rs0 += pv;
          }
        }
        l[t] += rs0 + rs1;
#pragma unroll
        for (int ck = 0; ck < 4; ck++) {
          ushort4v pk;
#pragma unroll
          for (int r = 0; r < 4; r++) pk[r] = f2bf(sc[t][ck][r]);
          *reinterpret_cast<ushort4v*>(&P[wave][t][lr][ck * 16 + lg * 4]) = pk;
        }
      }

      // 5) PV kk=0
      __builtin_amdgcn_s_setprio(1);
#pragma unroll
      for (int t = 0; t < 2; t++) {
        const bf16x8 pf = *reinterpret_cast<const bf16x8*>(&P[wave][t][lr][lg * 8]);
#pragma unroll
        for (int sub = 0; sub < 8; sub++)
          o[t][sub] = mfma16(vf[sub], pf, o[t][sub]);
      }
      __builtin_amdgcn_s_setprio(0);
      // V^T kk=1, PV kk=1
#pragma unroll
      for (int sub = 0; sub < 8; sub++)
        vf[sub] = *reinterpret_cast<const bf16x8*>(
            vfp + ((size_t)((kt * 2 + 1) * 8 + sub) << 9) + (lane << 3));
      __builtin_amdgcn_s_setprio(1);
#pragma unroll
      for (int t = 0; t < 2; t++) {
        const bf16x8 pf = *reinterpret_cast<const bf16x8*>(&P[wave][t][lr][32 + lg * 8]);
#pragma unroll
        for (int sub = 0; sub < 8; sub++)
          o[t][sub] = mfma16(vf[sub], pf, o[t][sub]);
      }
      __builtin_amdgcn_s_setprio(0);
    }

    // cross-lane l sum (once per phase)
#pragma unroll
    for (int t = 0; t < 2; t++) {
      l[t] += __shfl_xor(l[t], 16);
      l[t] += __shfl_xor(l[t], 32);
    }

    // publish normalized partials (ALL waves); weight = l
#pragma unroll
    for (int t = 0; t < 2; t++) {
      const float inv = (l[t] > 0.f) ? 1.0f / l[t] : 0.f;
#pragma unroll
      for (int sub = 0; sub < 8; sub++) {
        ushort4v pk;
#pragma unroll
        for (int r = 0; r < 4; r++) pk[r] = f2bf(o[t][sub][r] * inv);
        *reinterpret_cast<ushort4v*>(&Xo[wave][t * 16 + lr][sub * 16 + lg * 4]) = pk;
      }
      if (lg == 0) Xml[wave][t * 16 + lr] = l[t];
    }
    __syncthreads();

    // 4-way merge: wave handles rows [wave*8, wave*8+8); 16 d-values/thread
    {
      const int mrow = wave * 8 + (lane >> 3);
      float c[4], csum = 0.f;
#pragma unroll
      for (int w = 0; w < 4; w++) { c[w] = Xml[w][mrow]; csum += c[w]; }
      const float invT = 1.0f / csum;
#pragma unroll
      for (int half = 0; half < 2; half++) {
        const int dc = (lane & 7) + half * 8;
        float acc[8] = {};
#pragma unroll
        for (int w = 0; w < 4; w++) {
          const ushort8 v = *reinterpret_cast<const ushort8*>(&Xo[w][mrow][dc * 8]);
#pragma unroll
          for (int e = 0; e < 8; e++) acc[e] += c[w] * bf2f(v[e]);
        }
        ushort8 outv;
#pragma unroll
        for (int e = 0; e < 8; e++) outv[e] = f2bf(acc[e] * invT);
        *reinterpret_cast<ushort8*>(
            att + (size_t)(b * SS_ + rt * 32 + mrow) * (NH_ * VD_) + h * VD_ + dc * 8) = outv;
      }
    }
    __syncthreads();
  }
}

// ---------------- launcher ----------------

extern "C" void kernel_launch(void* const* d_in, const int* in_sizes, int n_in,
                              void* d_out, int out_size, void* d_ws, size_t ws_size,
                              hipStream_t stream) {
  const float* x    = (const float*)d_in[0];
  const float* pe   = (const float*)d_in[3];
  const float* wq_w = (const float*)d_in[4];
  const float* wq_b = (const float*)d_in[5];
  const float* wk_w = (const float*)d_in[6];
  const float* wk_b = (const float*)d_in[7];
  const float* wv_w = (const float*)d_in[8];
  const float* wv_b = (const float*)d_in[9];
  const float* wo_w = (const float*)d_in[10];
  const float* wo_b = (const float*)d_in[11];
  float* out = (float*)d_out;

  char* ws = (char*)d_ws;
  unsigned short* x_bf   = (unsigned short*)(ws);                 // 4 MB
  unsigned short* wqkv_t = (unsigned short*)(ws + 4194304);       // 3 MB
  unsigned short* wo_t   = (unsigned short*)(ws + 7340032);       // 1 MB
  float*          qkv_b  = (float*)(ws + 8388608);                // 12 KB
  unsigned short* qb     = (unsigned short*)(ws + 8400896);       // 8 MB (Qf)
  unsigned short* kb     = (unsigned short*)(ws + 16789504);      // 8 MB (Kf)
  unsigned short* vtb    = (unsigned short*)(ws + 25178112);      // 8 MB (Vf)
  unsigned short* attb   = (unsigned short*)(ws + 33566720);      // 8 MB

  k_prep<<<2572, 256, 0, stream>>>(x, x_bf, wq_w, wk_w, wv_w, wqkv_t,
                                   wo_w, wo_t, wq_b, wk_b, wv_b, qkv_b);

  dim3 g1(24, 32);
  k_gemm_qkv<<<g1, 256, 0, stream>>>(x_bf, wqkv_t, qkv_b, 512, qb, kb, vtb);

  dim3 g2(NH_, 32, BB_);  // x=head -> XCD = head; uniform-work blocks
  k_attn<<<g2, 256, 0, stream>>>(qb, kb, vtb, pe, attb);

  dim3 g3(8, 32);  // 128M x 64N tiles -> 256 blocks (full machine)
  k_gemm_o64<<<g3, 256, 0, stream>>>(attb, wo_t, wo_b, 1024, out);
}

// Round 21
// 97.977 us; speedup vs baseline: 1.2486x; 1.0051x over previous
//
#include <hip/hip_runtime.h>
#include <hip/hip_bf16.h>
#include <stdint.h>

#define BB_ 2
#define SS_ 2048
#define DIM_ 512
#define NH_ 8
#define QK_ 128
#define VD_ 128

typedef __attribute__((ext_vector_type(8))) short bf16x8;
typedef __attribute__((ext_vector_type(4))) float f32x4;
typedef __attribute__((ext_vector_type(8))) unsigned short ushort8;
typedef __attribute__((ext_vector_type(4))) unsigned short ushort4v;

__device__ __forceinline__ unsigned short f2bf(float f) {
  union { float f; unsigned int u; } v; v.f = f;
  unsigned int r = v.u + 0x7FFFu + ((v.u >> 16) & 1u);  // RNE
  return (unsigned short)(r >> 16);
}

__device__ __forceinline__ float bf2f(unsigned short u) {
  union { unsigned int u; float f; } v; v.u = ((unsigned int)u) << 16;
  return v.f;
}

__device__ __forceinline__ f32x4 mfma16(bf16x8 a, bf16x8 b, f32x4 c) {
  return __builtin_amdgcn_mfma_f32_16x16x32_bf16(a, b, c, 0, 0, 0);
}

// ---------------- fused prep kernel (x-convert + 4 transposes + bias) ----------------

__device__ void transpose_tile(const float* __restrict__ src, unsigned short* __restrict__ dst,
                               int R, int C, int c0, int r0, int tid, float (*t)[65]) {
  const int rr = tid >> 4, cc4 = (tid & 15) * 4;
#pragma unroll
  for (int p = 0; p < 4; p++) {
    float4 v = *reinterpret_cast<const float4*>(src + (size_t)(r0 + rr + p * 16) * C + c0 + cc4);
    t[rr + p * 16][cc4 + 0] = v.x; t[rr + p * 16][cc4 + 1] = v.y;
    t[rr + p * 16][cc4 + 2] = v.z; t[rr + p * 16][cc4 + 3] = v.w;
  }
  __syncthreads();
  const int cl = tid >> 2, rb = (tid & 3) * 16;
#pragma unroll
  for (int g = 0; g < 2; g++) {
    ushort8 o;
#pragma unroll
    for (int j = 0; j < 8; j++) o[j] = f2bf(t[rb + g * 8 + j][cl]);
    *reinterpret_cast<ushort8*>(dst + (size_t)(c0 + cl) * R + r0 + rb + g * 8) = o;
  }
}

__global__ void k_prep(const float* __restrict__ x, unsigned short* __restrict__ xb,
                       const float* __restrict__ wq, const float* __restrict__ wk,
                       const float* __restrict__ wv, unsigned short* __restrict__ wqkv_t,
                       const float* __restrict__ wo, unsigned short* __restrict__ wo_t,
                       const float* __restrict__ bq, const float* __restrict__ bk,
                       const float* __restrict__ bv, float* __restrict__ bias_out) {
  __shared__ float t[64][65];
  const int bid = blockIdx.x, tid = threadIdx.x;
  if (bid < 2048) {                       // x fp32 -> bf16, 4 elems/thread
    const int i = bid * 256 + tid;
    float4 v = reinterpret_cast<const float4*>(x)[i];
    ushort4v o;
    o[0] = f2bf(v.x); o[1] = f2bf(v.y); o[2] = f2bf(v.z); o[3] = f2bf(v.w);
    reinterpret_cast<ushort4v*>(xb)[i] = o;
  } else if (bid < 2432) {                // wq|wk|wv [512][1024] -> [1024][512]^T bf16
    const int tt0 = bid - 2048;
    const int w = tt0 >> 7, tt = tt0 & 127;
    const float* src = (w == 0) ? wq : (w == 1) ? wk : wv;
    transpose_tile(src, wqkv_t + (size_t)w * 1024 * 512, 512, 1024,
                   (tt & 15) * 64, (tt >> 4) * 64, tid, t);
  } else if (bid < 2560) {                // wo [1024][512] -> [512][1024]^T bf16
    const int tt = bid - 2432;
    transpose_tile(wo, wo_t, 1024, 512, (tt & 7) * 64, (tt >> 3) * 64, tid, t);
  } else {                                // bias concat
    const int i = (bid - 2560) * 256 + tid;
    if (i < 1024) bias_out[i] = bq[i];
    else if (i < 2048) bias_out[i] = bk[i - 1024];
    else if (i < 3072) bias_out[i] = bv[i - 2048];
  }
}

// ---------------- QKV GEMM (A row-major [M][K], BT row-major [N][K], both bf16) ----------------
// Staging via global_load_lds width-16. Writes pre-swizzled MFMA-fragment
// layouts for attention; q pre-scaled by 1/sqrt(128).

__global__ __launch_bounds__(256) void k_gemm_qkv(
    const unsigned short* __restrict__ A, const unsigned short* __restrict__ BT,
    const float* __restrict__ bias, int K,
    unsigned short* __restrict__ oq, unsigned short* __restrict__ ok,
    unsigned short* __restrict__ ovt) {
  __shared__ __align__(16) unsigned short Al[128][32];
  __shared__ __align__(16) unsigned short Bl[128][32];
  const int tid = threadIdx.x;
  const int lane = tid & 63, wave = tid >> 6;
  const int wm = wave >> 1, wn = wave & 1;
  const int lr = lane & 15, lg = lane >> 4;
  const int m0 = blockIdx.y * 128, n0 = blockIdx.x * 128;
  f32x4 acc[4][4] = {};
  const int srow = lane >> 2, scol = (lane & 3) * 8;

  for (int k0 = 0; k0 < K; k0 += 32) {
    __syncthreads();
    {
      const unsigned short* ga = A + (size_t)(m0 + wave * 16 + srow) * K + k0 + scol;
      __builtin_amdgcn_global_load_lds((const unsigned int*)ga,
                                       (unsigned int*)&Al[wave * 16][0], 16, 0, 0);
      __builtin_amdgcn_global_load_lds((const unsigned int*)(ga + (size_t)64 * K),
                                       (unsigned int*)&Al[wave * 16 + 64][0], 16, 0, 0);
      const unsigned short* gb = BT + (size_t)(n0 + wave * 16 + srow) * K + k0 + scol;
      __builtin_amdgcn_global_load_lds((const unsigned int*)gb,
                                       (unsigned int*)&Bl[wave * 16][0], 16, 0, 0);
      __builtin_amdgcn_global_load_lds((const unsigned int*)(gb + (size_t)64 * K),
                                       (unsigned int*)&Bl[wave * 16 + 64][0], 16, 0, 0);
    }
    __syncthreads();
    bf16x8 af[4], bfr[4];
#pragma unroll
    for (int i = 0; i < 4; i++)
      af[i] = *reinterpret_cast<const bf16x8*>(&Al[wm * 64 + i * 16 + lr][lg * 8]);
#pragma unroll
    for (int i = 0; i < 4; i++)
      bfr[i] = *reinterpret_cast<const bf16x8*>(&Bl[wn * 64 + i * 16 + lr][lg * 8]);
#pragma unroll
    for (int i = 0; i < 4; i++)
#pragma unroll
      for (int j = 0; j < 4; j++)
        acc[i][j] = mfma16(af[i], bfr[j], acc[i][j]);
  }

#pragma unroll
  for (int i = 0; i < 4; i++) {
#pragma unroll
    for (int j = 0; j < 4; j++) {
      const int n = n0 + wn * 64 + j * 16 + lr;
      const float bv = bias[n];
      const int mb = m0 + wm * 64 + i * 16 + lg * 4;
      const int region = n >> 10;
      const int h = (n & 1023) >> 7, d = n & 127;
      const int bb = mb >> 11, s0 = mb & 2047;
      const size_t hb = (size_t)(bb * NH_ + h) << 18;
      if (region == 2) {
        ushort4v pk;
#pragma unroll
        for (int r = 0; r < 4; r++) pk[r] = f2bf(acc[i][j][r] + bv);
        const int s32 = s0 >> 5, sg = (s0 >> 3) & 3, e0 = s0 & 7;
        const size_t off = hb + (size_t)(((s32 * 8 + (d >> 4)) * 4 + sg) * 128 + (d & 15) * 8 + e0);
        *reinterpret_cast<ushort4v*>(ovt + off) = pk;
      } else {
        unsigned short* dst = ((region == 0) ? oq : ok) + hb;
        const float qs = (region == 0) ? 0.08838834764831845f : 1.0f;
        const int rt_ = s0 >> 4, c_ = d >> 5, lg_ = (d >> 3) & 3, e_ = d & 7;
        const int lrb = s0 & 15;
#pragma unroll
        for (int r = 0; r < 4; r++)
          dst[(size_t)(((rt_ * 4 + c_) * 64 + lg_ * 16 + lrb + r) * 8 + e_)] =
              f2bf((acc[i][j][r] + bv) * qs);
      }
    }
  }
}

// ---------------- output GEMM: 128M x 64N tiles -> 256 blocks (full machine) ----------------

__global__ __launch_bounds__(256) void k_gemm_o64(
    const unsigned short* __restrict__ A, const unsigned short* __restrict__ BT,
    const float* __restrict__ bias, int K, float* __restrict__ of) {
  __shared__ __align__(16) unsigned short Al[128][32];
  __shared__ __align__(16) unsigned short Bl[64][32];
  const int tid = threadIdx.x;
  const int lane = tid & 63, wave = tid >> 6;
  const int lr = lane & 15, lg = lane >> 4;
  const int m0 = blockIdx.y * 128, n0 = blockIdx.x * 64;
  f32x4 acc[2][4] = {};
  const int srow = lane >> 2, scol = (lane & 3) * 8;

  for (int k0 = 0; k0 < K; k0 += 32) {
    __syncthreads();
    {
      const unsigned short* ga = A + (size_t)(m0 + wave * 16 + srow) * K + k0 + scol;
      __builtin_amdgcn_global_load_lds((const unsigned int*)ga,
                                       (unsigned int*)&Al[wave * 16][0], 16, 0, 0);
      __builtin_amdgcn_global_load_lds((const unsigned int*)(ga + (size_t)64 * K),
                                       (unsigned int*)&Al[wave * 16 + 64][0], 16, 0, 0);
      const unsigned short* gb = BT + (size_t)(n0 + wave * 16 + srow) * K + k0 + scol;
      __builtin_amdgcn_global_load_lds((const unsigned int*)gb,
                                       (unsigned int*)&Bl[wave * 16][0], 16, 0, 0);
    }
    __syncthreads();
    bf16x8 af[2], bfr[4];
#pragma unroll
    for (int i = 0; i < 2; i++)
      af[i] = *reinterpret_cast<const bf16x8*>(&Al[wave * 32 + i * 16 + lr][lg * 8]);
#pragma unroll
    for (int j = 0; j < 4; j++)
      bfr[j] = *reinterpret_cast<const bf16x8*>(&Bl[j * 16 + lr][lg * 8]);
#pragma unroll
    for (int i = 0; i < 2; i++)
#pragma unroll
      for (int j = 0; j < 4; j++)
        acc[i][j] = mfma16(af[i], bfr[j], acc[i][j]);
  }

#pragma unroll
  for (int i = 0; i < 2; i++) {
#pragma unroll
    for (int j = 0; j < 4; j++) {
      const int n = n0 + j * 16 + lr;
      const float bv = bias[n];
      const int mb = m0 + wave * 32 + i * 16 + lg * 4;
#pragma unroll
      for (int r = 0; r < 4; r++)
        of[(size_t)(mb + r) * DIM_ + n] = acc[i][j][r] + bv;
    }
  }
}

// ---------------- flash attention: uniform-work blocks, 4-way split-K, m=0 softmax ----------------
// R20 body + diagonal-tile peel: the causal compare (32 cmp+cndmask/iter) only
// matters on the LAST tile of the wave owning the diagonal; the main loop now
// runs mask-free, and the peeled final iteration applies the mask.

__global__ __launch_bounds__(256, 2) void k_attn(
    const unsigned short* __restrict__ q, const unsigned short* __restrict__ k,
    const unsigned short* __restrict__ vt, const float* __restrict__ pe,
    unsigned short* __restrict__ att) {
  __shared__ __align__(16) unsigned short P[4][2][16][72];   // 18 KB, wave-private
  __shared__ __align__(16) unsigned short Xo[4][32][136];    // 34.8 KB partials
  __shared__ float Xml[4][32];                               // l only

  const int h = blockIdx.x, p = blockIdx.y, b = blockIdx.z;
  const int lane = threadIdx.x & 63, wave = threadIdx.x >> 6;
  const int lr = lane & 15, lg = lane >> 4;

  const size_t hb = (size_t)(b * NH_ + h) << 18;
  const unsigned short* qfp = q + hb;
  const unsigned short* kfp = k + hb;
  const unsigned short* vfp = vt + hb;
  const float* peh = pe + (size_t)h * SS_ * SS_;

  for (int phase = 0; phase < 2; phase++) {
    const int rt = phase ? (63 - p) : p;     // q-tile32 index
    const int myq0 = rt * 32 + lr;           // tile t's q-row = myq0 + t*16
    const float* pep = peh + (size_t)myq0 * SS_;

    // Q fragments (pre-scaled), coalesced
    bf16x8 qf[2][4];
#pragma unroll
    for (int t = 0; t < 2; t++)
#pragma unroll
      for (int c = 0; c < 4; c++)
        qf[t][c] = *reinterpret_cast<const bf16x8*>(
            qfp + ((size_t)((rt * 2 + t) * 4 + c) << 9) + (lane << 3));

    f32x4 o[2][8] = {};
    float l[2] = {0.f, 0.f};    // per-lane partial row-sums

    const int nkt = (rt >> 1) + 1;
    const int kt_lo = (nkt * wave) >> 2;
    const int kt_hi = (nkt * (wave + 1)) >> 2;
    // peel the diagonal tile (only wave 3 owns it; kt_hi==nkt only then)
    const int kt_mid = (kt_hi == nkt) ? (kt_hi - 1) : kt_hi;

#define ATTN_TILE_BODY(KT, MASKED)                                                     \
    {                                                                                  \
      const int kbase = (KT) * 64;                                                     \
      f32x4 sc[2][4];                                                                  \
      _Pragma("unroll")                                                                \
      for (int t = 0; t < 2; t++)                                                      \
        _Pragma("unroll")                                                              \
        for (int ck = 0; ck < 4; ck++)                                                 \
          sc[t][ck] = *reinterpret_cast<const f32x4*>(                                 \
              pep + (size_t)(t * 16) * SS_ + kbase + ck * 16 + lg * 4);                \
      __builtin_amdgcn_s_setprio(1);                                                   \
      _Pragma("unroll")                                                                \
      for (int ck = 0; ck < 4; ck++) {                                                 \
        _Pragma("unroll")                                                              \
        for (int c = 0; c < 4; c++) {                                                  \
          const bf16x8 kf = *reinterpret_cast<const bf16x8*>(                          \
              kfp + ((size_t)(((KT) * 4 + ck) * 4 + c) << 9) + (lane << 3));           \
          sc[0][ck] = mfma16(kf, qf[0][c], sc[0][ck]);                                 \
          sc[1][ck] = mfma16(kf, qf[1][c], sc[1][ck]);                                 \
        }                                                                              \
      }                                                                                \
      __builtin_amdgcn_s_setprio(0);                                                   \
      bf16x8 vf[8];                                                                    \
      _Pragma("unroll")                                                                \
      for (int sub = 0; sub < 8; sub++)                                                \
        vf[sub] = *reinterpret_cast<const bf16x8*>(                                    \
            vfp + ((size_t)(((KT) * 2) * 8 + sub) << 9) + (lane << 3));                \
      _Pragma("unroll")                                                                \
      for (int t = 0; t < 2; t++) {                                                    \
        const int mq = myq0 + t * 16;                                                  \
        float rs0 = 0.f, rs1 = 0.f;                                                    \
        _Pragma("unroll")                                                              \
        for (int ck = 0; ck < 4; ck++) {                                               \
          _Pragma("unroll")                                                            \
          for (int r = 0; r < 4; r++) {                                                \
            float v = sc[t][ck][r];                                                    \
            if (MASKED && (kbase + ck * 16 + lg * 4 + r) > mq) v = -1e30f;             \
            const float pv = __expf(v);                                                \
            sc[t][ck][r] = pv;                                                         \
            if (ck & 1) rs1 += pv; else rs0 += pv;                                     \
          }                                                                            \
        }                                                                              \
        l[t] += rs0 + rs1;                                                             \
        _Pragma("unroll")                                                              \
        for (int ck = 0; ck < 4; ck++) {                                               \
          ushort4v pk;                                                                 \
          _Pragma("unroll")                                                            \
          for (int r = 0; r < 4; r++) pk[r] = f2bf(sc[t][ck][r]);                      \
          *reinterpret_cast<ushort4v*>(&P[wave][t][lr][ck * 16 + lg * 4]) = pk;        \
        }                                                                              \
      }                                                                                \
      __builtin_amdgcn_s_setprio(1);                                                   \
      _Pragma("unroll")                                                                \
      for (int t = 0; t < 2; t++) {                                                    \
        const bf16x8 pf = *reinterpret_cast<const bf16x8*>(&P[wave][t][lr][lg * 8]);   \
        _Pragma("unroll")                                                              \
        for (int sub = 0; sub < 8; sub++)                                              \
          o[t][sub] = mfma16(vf[sub], pf, o[t][sub]);                                  \
      }                                                                                \
      __builtin_amdgcn_s_setprio(0);                                                   \
      _Pragma("unroll")                                                                \
      for (int sub = 0; sub < 8; sub++)                                                \
        vf[sub] = *reinterpret_cast<const bf16x8*>(                                    \
            vfp + ((size_t)(((KT) * 2 + 1) * 8 + sub) << 9) + (lane << 3));            \
      __builtin_amdgcn_s_setprio(1);                                                   \
      _Pragma("unroll")                                                                \
      for (int t = 0; t < 2; t++) {                                                    \
        const bf16x8 pf = *reinterpret_cast<const bf16x8*>(                            \
            &P[wave][t][lr][32 + lg * 8]);                                             \
        _Pragma("unroll")                                                              \
        for (int sub = 0; sub < 8; sub++)                                              \
          o[t][sub] = mfma16(vf[sub], pf, o[t][sub]);                                  \
      }                                                                                \
      __builtin_amdgcn_s_setprio(0);                                                   \
    }

    for (int kt = kt_lo; kt < kt_mid; kt++) ATTN_TILE_BODY(kt, false)
    if (kt_mid < kt_hi) ATTN_TILE_BODY(kt_mid, true)

#undef ATTN_TILE_BODY

    // cross-lane l sum (once per phase)
#pragma unroll
    for (int t = 0; t < 2; t++) {
      l[t] += __shfl_xor(l[t], 16);
      l[t] += __shfl_xor(l[t], 32);
    }

    // publish normalized partials (ALL waves); weight = l
#pragma unroll
    for (int t = 0; t < 2; t++) {
      const float inv = (l[t] > 0.f) ? 1.0f / l[t] : 0.f;
#pragma unroll
      for (int sub = 0; sub < 8; sub++) {
        ushort4v pk;
#pragma unroll
        for (int r = 0; r < 4; r++) pk[r] = f2bf(o[t][sub][r] * inv);
        *reinterpret_cast<ushort4v*>(&Xo[wave][t * 16 + lr][sub * 16 + lg * 4]) = pk;
      }
      if (lg == 0) Xml[wave][t * 16 + lr] = l[t];
    }
    __syncthreads();

    // 4-way merge: wave handles rows [wave*8, wave*8+8); 16 d-values/thread
    {
      const int mrow = wave * 8 + (lane >> 3);
      float c[4], csum = 0.f;
#pragma unroll
      for (int w = 0; w < 4; w++) { c[w] = Xml[w][mrow]; csum += c[w]; }
      const float invT = 1.0f / csum;
#pragma unroll
      for (int half = 0; half < 2; half++) {
        const int dc = (lane & 7) + half * 8;
        float acc[8] = {};
#pragma unroll
        for (int w = 0; w < 4; w++) {
          const ushort8 v = *reinterpret_cast<const ushort8*>(&Xo[w][mrow][dc * 8]);
#pragma unroll
          for (int e = 0; e < 8; e++) acc[e] += c[w] * bf2f(v[e]);
        }
        ushort8 outv;
#pragma unroll
        for (int e = 0; e < 8; e++) outv[e] = f2bf(acc[e] * invT);
        *reinterpret_cast<ushort8*>(
            att + (size_t)(b * SS_ + rt * 32 + mrow) * (NH_ * VD_) + h * VD_ + dc * 8) = outv;
      }
    }
    __syncthreads();
  }
}

// ---------------- launcher ----------------

extern "C" void kernel_launch(void* const* d_in, const int* in_sizes, int n_in,
                              void* d_out, int out_size, void* d_ws, size_t ws_size,
                              hipStream_t stream) {
  const float* x    = (const float*)d_in[0];
  const float* pe   = (const float*)d_in[3];
  const float* wq_w = (const float*)d_in[4];
  const float* wq_b = (const float*)d_in[5];
  const float* wk_w = (const float*)d_in[6];
  const float* wk_b = (const float*)d_in[7];
  const float* wv_w = (const float*)d_in[8];
  const float* wv_b = (const float*)d_in[9];
  const float* wo_w = (const float*)d_in[10];
  const float* wo_b = (const float*)d_in[11];
  float* out = (float*)d_out;

  char* ws = (char*)d_ws;
  unsigned short* x_bf   = (unsigned short*)(ws);                 // 4 MB
  unsigned short* wqkv_t = (unsigned short*)(ws + 4194304);       // 3 MB
  unsigned short* wo_t   = (unsigned short*)(ws + 7340032);       // 1 MB
  float*          qkv_b  = (float*)(ws + 8388608);                // 12 KB
  unsigned short* qb     = (unsigned short*)(ws + 8400896);       // 8 MB (Qf)
  unsigned short* kb     = (unsigned short*)(ws + 16789504);      // 8 MB (Kf)
  unsigned short* vtb    = (unsigned short*)(ws + 25178112);      // 8 MB (Vf)
  unsigned short* attb   = (unsigned short*)(ws + 33566720);      // 8 MB

  k_prep<<<2572, 256, 0, stream>>>(x, x_bf, wq_w, wk_w, wv_w, wqkv_t,
                                   wo_w, wo_t, wq_b, wk_b, wv_b, qkv_b);

  dim3 g1(24, 32);
  k_gemm_qkv<<<g1, 256, 0, stream>>>(x_bf, wqkv_t, qkv_b, 512, qb, kb, vtb);

  dim3 g2(NH_, 32, BB_);  // x=head -> XCD = head; uniform-work blocks
  k_attn<<<g2, 256, 0, stream>>>(qb, kb, vtb, pe, attb);

  dim3 g3(8, 32);  // 128M x 64N tiles -> 256 blocks
  k_gemm_o64<<<g3, 256, 0, stream>>>(attb, wo_t, wo_b, 1024, out);
}